// Round 20
// baseline (176.519 us; speedup 1.0000x reference)
//
#include <hip/hip_runtime.h>
#include <stdint.h>

#define BTOK 32768
#define DIN 256
#define DHID 512
#define DOUT 256
#define NEXP 16
#define BM 128
#define CH 64
#define NCH 8

typedef __attribute__((ext_vector_type(8))) short bf16x8;
typedef __attribute__((ext_vector_type(16))) float f32x16;

__device__ __forceinline__ unsigned short f2bf(float f){
  unsigned u = __builtin_bit_cast(unsigned, f);
  u = u + 0x7FFFu + ((u >> 16) & 1u);      // RNE, finite inputs only
  return (unsigned short)(u >> 16);
}
__device__ __forceinline__ float bf2f(unsigned short h){
  return __builtin_bit_cast(float, (unsigned)h << 16);
}
__device__ __forceinline__ void gload16(const void* g, void* l){
  __builtin_amdgcn_global_load_lds((const __attribute__((address_space(1))) unsigned int*)g,
                                   (__attribute__((address_space(3))) unsigned int*)l, 16, 0, 0);
}

// ---------------- fused prep: weight transposes + gating in ONE launch.
// bid < 2048 : W1 [e][256 i][512 h] -> W1t [e][512 h][256 i]
// bid < 4096 : W2 [e][512 h][256 o] -> W2c [e][8 c][256 o][64 h]
// bid >= 4096: gating, 64 tokens/block (fp32 logits, exact top-2)
__global__ __launch_bounds__(256) void prep_kernel(const float* __restrict__ x,
                                                   const float* __restrict__ Wg,
                                                   const float* __restrict__ bg,
                                                   const float* __restrict__ W1,
                                                   const float* __restrict__ W2,
                                                   unsigned short* __restrict__ W1t,
                                                   unsigned short* __restrict__ W2c,
                                                   unsigned short* __restrict__ x_bf,
                                                   int* __restrict__ top_idx,
                                                   float* __restrict__ top_w,
                                                   int* __restrict__ counts){
  __shared__ float tsh[32][33];
  __shared__ float WgT[16][256];
  __shared__ int hist[16];
  int bid = blockIdx.x, tid = threadIdx.x;
  int lx = tid & 31, ly = tid >> 5;

  if (bid < 2048){
    int bx = bid & 15, by = (bid >> 4) & 7, bz = bid >> 7;
    int r0 = by * 32, c0 = bx * 32;            // r0 over i (256), c0 over h (512)
    const float* s = W1 + (size_t)bz * 256 * 512;
    unsigned short* d = W1t + (size_t)bz * 256 * 512;
#pragma unroll
    for (int i = 0; i < 4; i++){ int r = ly + i * 8; tsh[r][lx] = s[(size_t)(r0 + r) * 512 + c0 + lx]; }
    __syncthreads();
#pragma unroll
    for (int i = 0; i < 4; i++){ int r = ly + i * 8; d[(size_t)(c0 + r) * 256 + r0 + lx] = f2bf(tsh[lx][r]); }
  } else if (bid < 4096){
    int b2 = bid - 2048;
    int bx = b2 & 7, by = (b2 >> 3) & 15, bz = b2 >> 7;
    int r0 = by * 32, c0 = bx * 32;            // r0 over h (512), c0 over o (256)
    const float* s = W2 + (size_t)bz * DHID * DOUT;
    unsigned short* d = W2c + (size_t)bz * DHID * DOUT + (r0 >> 6) * (DOUT * CH) + (r0 & 32);
#pragma unroll
    for (int i = 0; i < 4; i++){ int r = ly + i * 8; tsh[r][lx] = s[(size_t)(r0 + r) * DOUT + c0 + lx]; }
    __syncthreads();
#pragma unroll
    for (int i = 0; i < 4; i++){ int rr = ly + i * 8; d[(size_t)(c0 + rr) * CH + lx] = f2bf(tsh[lx][rr]); }
  } else {
    int gb = bid - 4096;
#pragma unroll
    for (int j = 0; j < 4; j++){
      float4 wv = *(const float4*)(Wg + tid * 16 + j * 4);
      WgT[j * 4 + 0][tid] = wv.x; WgT[j * 4 + 1][tid] = wv.y;
      WgT[j * 4 + 2][tid] = wv.z; WgT[j * 4 + 3][tid] = wv.w;
    }
    if (tid < 16) hist[tid] = 0;
    __syncthreads();
    int wid = tid >> 6, lane = tid & 63;
    for (int t = 0; t < 16; t++){
      int tok = gb * 64 + wid * 16 + t;
      const float4 xv = *(const float4*)(x + (size_t)tok * DIN + lane * 4);
      ushort4 xb; xb.x = f2bf(xv.x); xb.y = f2bf(xv.y); xb.z = f2bf(xv.z); xb.w = f2bf(xv.w);
      *(ushort4*)(x_bf + (size_t)tok * DIN + lane * 4) = xb;
      float logit[16];
#pragma unroll
      for (int e = 0; e < 16; e++){
        const float4 wv = *(const float4*)(&WgT[e][lane * 4]);
        float v = xv.x * wv.x + xv.y * wv.y + xv.z * wv.z + xv.w * wv.w;
#pragma unroll
        for (int off = 32; off; off >>= 1) v += __shfl_xor(v, off, 64);
        logit[e] = v + bg[e];
      }
      if (lane == 0){
        int i1 = 0; float v1 = logit[0];
#pragma unroll
        for (int e = 1; e < 16; e++) if (logit[e] > v1){ v1 = logit[e]; i1 = e; }
        int i2 = -1; float v2 = -3.4e38f;
#pragma unroll
        for (int e = 0; e < 16; e++) if (e != i1 && logit[e] > v2){ v2 = logit[e]; i2 = e; }
        float tt = expf(v2 - v1);
        float w1 = 1.0f / (1.0f + tt);
        float w2 = tt / (1.0f + tt);
        top_idx[tok * 2] = i1; top_idx[tok * 2 + 1] = i2;
        top_w[tok * 2] = w1;  top_w[tok * 2 + 1] = w2;
        atomicAdd(&hist[i1], 1); atomicAdd(&hist[i2], 1);
      }
    }
    __syncthreads();
    if (tid < 16) atomicAdd(&counts[tid], hist[tid]);
  }
}

// ---------------- scatter: local scan of counts, block-aggregated reservation.
// pair_tok packs token | (k<<16).
__global__ __launch_bounds__(256) void scatter_kernel(const int* __restrict__ top_idx,
                                                      const float* __restrict__ top_w,
                                                      const int* __restrict__ counts,
                                                      int* __restrict__ cursor,
                                                      int* __restrict__ pair_tok,
                                                      float* __restrict__ pair_w){
  __shared__ int hist[16], base[16], rank[16], offs[16];
  int tid = threadIdx.x;
  if (tid < 16){ hist[tid] = 0; rank[tid] = 0; }
  __syncthreads();
  int t = blockIdx.x * 256 + tid;
  int e0 = top_idx[t * 2], e1 = top_idx[t * 2 + 1];
  float w0 = top_w[t * 2], w1 = top_w[t * 2 + 1];
  atomicAdd(&hist[e0], 1); atomicAdd(&hist[e1], 1);
  if (tid < 64){                      // wave 0: exclusive scan of counts
    int lane = tid;
    int c = (lane < 16) ? counts[lane] : 0;
    int s = c;
#pragma unroll
    for (int off = 1; off < 16; off <<= 1){ int o = __shfl_up(s, off, 64); if (lane >= off) s += o; }
    if (lane < 16) offs[lane] = s - c;
  }
  __syncthreads();
  if (tid < 16) base[tid] = offs[tid] + atomicAdd(&cursor[tid], hist[tid]);
  __syncthreads();
  int r0 = atomicAdd(&rank[e0], 1);
  int p0 = base[e0] + r0;
  pair_tok[p0] = t; pair_w[p0] = w0;
  int r1 = atomicAdd(&rank[e1], 1);
  int p1 = base[e1] + r1;
  pair_tok[p1] = t | (1 << 16); pair_w[p1] = w1;
}

// ---------------- fused 2-layer expert MLP (R19 internals + T5 setprio around
// MFMA clusters). 32x32 MFMA, 16-granule XOR swizzles, dbuf global_load_lds
// staging, raw barriers, persistent per-XCD stealing, in-kernel unit mapping.
__global__ __launch_bounds__(512, 1) void moe_gemm_kernel(
    const unsigned short* __restrict__ x_bf,   // [B][256]
    const unsigned short* __restrict__ W1t,    // [E][512 h][256 i]
    const unsigned short* __restrict__ W2c,    // [E][8 c][256 o][64 h]
    const float* __restrict__ b1,              // [E][512]
    const float* __restrict__ b2,              // [E][256]
    const int* __restrict__ pair_tok, const float* __restrict__ pair_w,
    const int* __restrict__ counts,
    int* __restrict__ xcd_cur,
    unsigned short* __restrict__ ypair){       // [B*2][256] bf16, token-major
  int xcd = blockIdx.x & 7;

  __shared__ unsigned short w1s[2][CH * 256];   // 2x32KB [64 hid][256 k], 512B rows, ^(hid&15)<<4
  __shared__ unsigned short w2s[2][256 * CH];   // 2x32KB [256 o][64 k], 256B row-pairs, ^(pair&15)<<4
  __shared__ unsigned short hs[BM * CH];        // 16KB [128 tok][64 h], 256B row-pairs, ^(pair&15)<<4
  __shared__ int s_map[6];
  __shared__ int s_u;

  int tid = threadIdx.x, wid = tid >> 6, lane = tid & 63;
  int l31 = lane & 31, l5 = lane >> 5;
  int mg = wid >> 1, hg = wid & 1;
  char* hsb = (char*)hs;

  // ---- derive this XCD's (expert, start, count) mapping from counts
  if (tid < 64){
    int c = (lane < 16) ? counts[lane] : 0;
    int s = c;
#pragma unroll
    for (int off = 1; off < 16; off <<= 1){ int o = __shfl_up(s, off, 64); if (lane >= off) s += o; }
    int start = s - c;
    int c0 = __shfl(c, xcd, 64),     st0 = __shfl(start, xcd, 64);
    int c1 = __shfl(c, xcd + 8, 64), st1 = __shfl(start, xcd + 8, 64);
    if (lane == 0){
      int nb0 = (c0 + BM - 1) >> 7, nb1 = (c1 + BM - 1) >> 7;
      s_map[0] = c0; s_map[1] = st0; s_map[2] = c1; s_map[3] = st1;
      s_map[4] = nb0; s_map[5] = nb0 + nb1;
    }
  }
  __syncthreads();
  int mc0 = s_map[0], mst0 = s_map[1], mc1 = s_map[2], mst1 = s_map[3];
  int nb0 = s_map[4], cnt = s_map[5];

  // pre-swizzled staging source offsets (linear LDS dest; +k*8192 preserves XOR bits)
  int o1, o2;
  { int r = tid >> 5; o1 = r * 512 + (((tid & 31) ^ (r & 15)) * 16); }
  { int p = tid >> 4; int q = (tid & 15) ^ (p & 15);
    o2 = (p * 2 + (q >> 3)) * 128 + (q & 7) * 16; }

  int hid = hg * 32 + l31;                 // chunk-local hid row this wave reads/writes
  int swzA = (hid & 15) << 4;
  const f32x16 fzero = {0.f,0.f,0.f,0.f,0.f,0.f,0.f,0.f,0.f,0.f,0.f,0.f,0.f,0.f,0.f,0.f};

  for (;;){
    if (tid == 0) s_u = atomicAdd(&xcd_cur[xcd], 1);
    __syncthreads();
    int u = s_u;
    if (u >= cnt) break;                   // uniform exit
    int e, rs, re;
    if (u < nb0){ e = xcd;     rs = mst0 + u * BM;         re = mst0 + mc0; }
    else        { e = xcd + 8; rs = mst1 + (u - nb0) * BM; re = mst1 + mc1; }
    const char* gW1 = (const char*)(W1t + (size_t)e * DHID * DIN);
    const char* gW2 = (const char*)(W2c + (size_t)e * DOUT * DHID);

#define STAGE(c, sl) {                                                    \
    const char* s1 = gW1 + (size_t)(c) * 32768;                           \
    const char* s2 = gW2 + (size_t)(c) * 32768;                           \
    char* d1 = (char*)w1s[sl]; char* d2 = (char*)w2s[sl];                 \
    _Pragma("unroll")                                                     \
    for (int k = 0; k < 4; k++){                                          \
      gload16(s1 + o1 + k * 8192, d1 + tid * 16 + k * 8192);              \
      gload16(s2 + o2 + k * 8192, d2 + tid * 16 + k * 8192);              \
    } }

    // ---- x rows (wave's 32 tokens) -> registers: 16 k-frags (64 VGPR)
    bf16x8 xr[16];
    {
      int g0 = rs + mg * 32 + l31;
      int gc = g0 < re ? g0 : (re - 1);
      int tok = pair_tok[gc] & 0xFFFF;
      const unsigned short* xrow = x_bf + (size_t)tok * DIN + l5 * 8;
#pragma unroll
      for (int ks = 0; ks < 16; ks++) xr[ks] = *(const bf16x8*)(xrow + ks * 16);
    }

    f32x16 acc[4];
    acc[0] = fzero; acc[1] = fzero; acc[2] = fzero; acc[3] = fzero;

    STAGE(0, 0);
    asm volatile("s_waitcnt vmcnt(0)" ::: "memory");
    __builtin_amdgcn_sched_barrier(0);
    __builtin_amdgcn_s_barrier();
    __builtin_amdgcn_sched_barrier(0);

    for (int c = 0; c < NCH; c++){
      int sl = c & 1;
      if (c + 1 < NCH) STAGE(c + 1, sl ^ 1);     // lands during this chunk

      float b1v = b1[e * DHID + c * CH + hid];

      // ---- phase A: h-tile[32 tok of mg][32 hid of hg], K=256, 2 dep-chains
      {
        const char* w1b = (const char*)w1s[sl];
        f32x16 h0 = fzero, h1 = fzero;
        __builtin_amdgcn_s_setprio(1);
#pragma unroll
        for (int ks = 0; ks < 16; ks += 2){
          bf16x8 bA = *(const bf16x8*)(w1b + hid * 512 + ((ks * 32 + l5 * 16) ^ swzA));
          bf16x8 bB = *(const bf16x8*)(w1b + hid * 512 + (((ks + 1) * 32 + l5 * 16) ^ swzA));
          h0 = __builtin_amdgcn_mfma_f32_32x32x16_bf16(xr[ks], bA, h0, 0, 0, 0);
          h1 = __builtin_amdgcn_mfma_f32_32x32x16_bf16(xr[ks + 1], bB, h1, 0, 0, 0);
        }
        __builtin_amdgcn_s_setprio(0);
        f32x16 hsum = h0 + h1;
        // relu(h+b1) -> hs; C/D: col=lane&31, row=(reg&3)+8*(reg>>2)+4*(lane>>5)
        int h2 = hg * 64 + l31 * 2;
#pragma unroll
        for (int r = 0; r < 16; r++){
          int tk = mg * 32 + (r & 3) + ((r >> 2) << 3) + (l5 << 2);
          float v = fmaxf(hsum[r] + b1v, 0.f);
          int adr = (tk >> 1) * 256 + ((((tk & 1) << 7) + h2) ^ (((tk >> 1) & 15) << 4));
          *(unsigned short*)(hsb + adr) = f2bf(v);
        }
      }
      asm volatile("s_waitcnt lgkmcnt(0)" ::: "memory");
      __builtin_amdgcn_sched_barrier(0);
      __builtin_amdgcn_s_barrier();
      __builtin_amdgcn_sched_barrier(0);

      // ---- phase B: y[32 tok of mg][128 out of hg] += h @ W2c (K=64)
      {
        const char* w2b = (const char*)w2s[sl];
        int tk = mg * 32 + l31;
        int hswz = ((tk >> 1) & 15) << 4;
        int hbase = (tk >> 1) * 256;
        int hhi = (tk & 1) << 7;
        __builtin_amdgcn_s_setprio(1);
#pragma unroll
        for (int ks = 0; ks < 4; ks++){
          bf16x8 ha = *(const bf16x8*)(hsb + hbase + ((hhi + ks * 32 + l5 * 16) ^ hswz));
#pragma unroll
          for (int ot = 0; ot < 4; ot++){
            int n = hg * 128 + ot * 32 + l31;
            int adr = (n >> 1) * 256 + ((((n & 1) << 7) + ks * 32 + l5 * 16) ^ (((n >> 1) & 15) << 4));
            bf16x8 bb = *(const bf16x8*)(w2b + adr);
            acc[ot] = __builtin_amdgcn_mfma_f32_32x32x16_bf16(ha, bb, acc[ot], 0, 0, 0);
          }
        }
        __builtin_amdgcn_s_setprio(0);
      }
      if (c + 1 < NCH){
        asm volatile("s_waitcnt vmcnt(0) lgkmcnt(0)" ::: "memory");
        __builtin_amdgcn_sched_barrier(0);
        __builtin_amdgcn_s_barrier();
        __builtin_amdgcn_sched_barrier(0);
      }
    }

    // ---- epilogue: fold gate weight + b2, store token-major bf16 rows
    {
      float b2v[4];
#pragma unroll
      for (int ot = 0; ot < 4; ot++) b2v[ot] = b2[e * DOUT + hg * 128 + ot * 32 + l31];
#pragma unroll
      for (int r = 0; r < 16; r++){
        int tl = mg * 32 + (r & 3) + ((r >> 2) << 3) + (l5 << 2);
        int gg = rs + tl;
        if (gg < re){
          int pt = pair_tok[gg];
          int yrow = (pt & 0xFFFF) * 2 + (pt >> 16);
          float w = pair_w[gg];
          unsigned short* yp = ypair + (size_t)yrow * DOUT + hg * 128 + l31;
#pragma unroll
          for (int ot = 0; ot < 4; ot++)
            yp[ot * 32] = f2bf(w * (acc[ot][r] + b2v[ot]));
        }
      }
    }
#undef STAGE
  }
}

// ---------------- combine: out[t] = yp[2t] + yp[2t+1], fully coalesced
__global__ __launch_bounds__(256) void combine_kernel(const unsigned short* __restrict__ yp,
                                                      float* __restrict__ out){
  int idx = blockIdx.x * 256 + threadIdx.x;
  int t = idx >> 6;
  int c4 = (idx & 63) << 2;
  ushort4 a = *(const ushort4*)(yp + (size_t)(t * 2) * DOUT + c4);
  ushort4 b = *(const ushort4*)(yp + (size_t)(t * 2 + 1) * DOUT + c4);
  float4 o;
  o.x = bf2f(a.x) + bf2f(b.x);
  o.y = bf2f(a.y) + bf2f(b.y);
  o.z = bf2f(a.z) + bf2f(b.z);
  o.w = bf2f(a.w) + bf2f(b.w);
  *(float4*)(out + (size_t)t * DOUT + c4) = o;
}

extern "C" void kernel_launch(void* const* d_in, const int* in_sizes, int n_in,
                              void* d_out, int out_size, void* d_ws, size_t ws_size,
                              hipStream_t stream){
  (void)in_sizes; (void)n_in; (void)out_size; (void)ws_size;
  const float* x  = (const float*)d_in[0];
  const float* Wg = (const float*)d_in[1];
  const float* bg = (const float*)d_in[2];
  const float* W1 = (const float*)d_in[3];
  const float* b1 = (const float*)d_in[4];
  const float* W2 = (const float*)d_in[5];
  const float* b2 = (const float*)d_in[6];
  float* out = (float*)d_out;
  char* ws = (char*)d_ws;

  unsigned short* x_bf  = (unsigned short*)(ws);                 // 16,777,216
  unsigned short* W1t   = (unsigned short*)(ws + 16777216);      //  4,194,304
  unsigned short* W2ck  = (unsigned short*)(ws + 20971520);      //  4,194,304
  unsigned short* ypair = (unsigned short*)(ws + 25165824);      // 33,554,432
  int*   top_idx  = (int*)  (ws + 58720256);
  float* top_w    = (float*)(ws + 58982400);
  int*   pair_tok = (int*)  (ws + 59244544);
  float* pair_w   = (float*)(ws + 59506688);
  int*   counts   = (int*)  (ws + 60030976);   // 16 ints
  int*   cursor   = (int*)  (ws + 60031040);   // 16 ints
  int*   xcd_cur  = (int*)  (ws + 60031104);   // 8 ints

  hipMemsetAsync(counts, 0, 192, stream);      // counts + cursor + xcd_cur
  prep_kernel<<<4608, 256, 0, stream>>>(x, Wg, bg, W1, W2, W1t, W2ck,
                                        x_bf, top_idx, top_w, counts);
  scatter_kernel<<<128, 256, 0, stream>>>(top_idx, top_w, counts, cursor, pair_tok, pair_w);
  moe_gemm_kernel<<<256, 512, 0, stream>>>(x_bf, W1t, W2ck, b1, b2, pair_tok, pair_w,
                                           counts, xcd_cur, ypair);
  combine_kernel<<<8192, 256, 0, stream>>>(ypair, out);
}

// Round 21
// 148.962 us; speedup vs baseline: 1.1850x; 1.1850x over previous
//
#include <hip/hip_runtime.h>
#include <stdint.h>

#define BTOK 32768
#define DIN 256
#define DHID 512
#define DOUT 256
#define NEXP 16
#define BM 128
#define CH 64
#define NCH 8

typedef __attribute__((ext_vector_type(8))) short bf16x8;
typedef __attribute__((ext_vector_type(16))) float f32x16;

__device__ __forceinline__ unsigned short f2bf(float f){
  unsigned u = __builtin_bit_cast(unsigned, f);
  u = u + 0x7FFFu + ((u >> 16) & 1u);      // RNE, finite inputs only
  return (unsigned short)(u >> 16);
}
__device__ __forceinline__ float bf2f(unsigned short h){
  return __builtin_bit_cast(float, (unsigned)h << 16);
}
__device__ __forceinline__ void gload16(const void* g, void* l){
  __builtin_amdgcn_global_load_lds((const __attribute__((address_space(1))) unsigned int*)g,
                                   (__attribute__((address_space(3))) unsigned int*)l, 16, 0, 0);
}

// ---------------- fused weight transposes (one launch, 4096 blocks, 4.2KB LDS)
// bid < 2048 : W1 [e][256 i][512 h] -> W1t [e][512 h][256 i]
// bid >= 2048: W2 [e][512 h][256 o] -> W2c [e][8 c][256 o][64 h] (chunk-major)
__global__ __launch_bounds__(256) void transpose_fused(const float* __restrict__ W1,
                                                       const float* __restrict__ W2,
                                                       unsigned short* __restrict__ W1t,
                                                       unsigned short* __restrict__ W2c){
  __shared__ float t[32][33];
  int bid = blockIdx.x, tid = threadIdx.x;
  int lx = tid & 31, ly = tid >> 5;
  if (bid < 2048){
    int bx = bid & 15, by = (bid >> 4) & 7, bz = bid >> 7;
    int r0 = by * 32, c0 = bx * 32;            // r0 over i (256), c0 over h (512)
    const float* s = W1 + (size_t)bz * 256 * 512;
    unsigned short* d = W1t + (size_t)bz * 256 * 512;
#pragma unroll
    for (int i = 0; i < 4; i++){ int r = ly + i * 8; t[r][lx] = s[(size_t)(r0 + r) * 512 + c0 + lx]; }
    __syncthreads();
#pragma unroll
    for (int i = 0; i < 4; i++){ int r = ly + i * 8; d[(size_t)(c0 + r) * 256 + r0 + lx] = f2bf(t[lx][r]); }
  } else {
    int b2 = bid - 2048;
    int bx = b2 & 7, by = (b2 >> 3) & 15, bz = b2 >> 7;
    int r0 = by * 32, c0 = bx * 32;            // r0 over h (512), c0 over o (256)
    const float* s = W2 + (size_t)bz * DHID * DOUT;
    unsigned short* d = W2c + (size_t)bz * DHID * DOUT + (r0 >> 6) * (DOUT * CH) + (r0 & 32);
#pragma unroll
    for (int i = 0; i < 4; i++){ int r = ly + i * 8; t[r][lx] = s[(size_t)(r0 + r) * DOUT + c0 + lx]; }
    __syncthreads();
#pragma unroll
    for (int i = 0; i < 4; i++){ int rr = ly + i * 8; d[(size_t)(c0 + rr) * CH + lx] = f2bf(t[lx][rr]); }
  }
}

// ---------------- gating: 512 blocks x 64 tokens; LDS-aggregated histogram
__global__ __launch_bounds__(256) void gating_kernel(const float* __restrict__ x,
                                                     const float* __restrict__ Wg,
                                                     const float* __restrict__ bg,
                                                     unsigned short* __restrict__ x_bf,
                                                     int* __restrict__ top_idx,
                                                     float* __restrict__ top_w,
                                                     int* __restrict__ counts){
  __shared__ float WgT[16][256];
  __shared__ int hist[16];
  int tid = threadIdx.x;
#pragma unroll
  for (int j = 0; j < 4; j++){
    float4 wv = *(const float4*)(Wg + tid * 16 + j * 4);
    WgT[j * 4 + 0][tid] = wv.x; WgT[j * 4 + 1][tid] = wv.y;
    WgT[j * 4 + 2][tid] = wv.z; WgT[j * 4 + 3][tid] = wv.w;
  }
  if (tid < 16) hist[tid] = 0;
  __syncthreads();
  int wid = tid >> 6, lane = tid & 63;

  for (int t = 0; t < 16; t++){
    int tok = blockIdx.x * 64 + wid * 16 + t;
    const float4 xv = *(const float4*)(x + (size_t)tok * DIN + lane * 4);
    ushort4 xb; xb.x = f2bf(xv.x); xb.y = f2bf(xv.y); xb.z = f2bf(xv.z); xb.w = f2bf(xv.w);
    *(ushort4*)(x_bf + (size_t)tok * DIN + lane * 4) = xb;
    float logit[16];
#pragma unroll
    for (int e = 0; e < 16; e++){
      const float4 wv = *(const float4*)(&WgT[e][lane * 4]);
      float v = xv.x * wv.x + xv.y * wv.y + xv.z * wv.z + xv.w * wv.w;
#pragma unroll
      for (int off = 32; off; off >>= 1) v += __shfl_xor(v, off, 64);
      logit[e] = v + bg[e];
    }
    if (lane == 0){
      int i1 = 0; float v1 = logit[0];
#pragma unroll
      for (int e = 1; e < 16; e++) if (logit[e] > v1){ v1 = logit[e]; i1 = e; }
      int i2 = -1; float v2 = -3.4e38f;
#pragma unroll
      for (int e = 0; e < 16; e++) if (e != i1 && logit[e] > v2){ v2 = logit[e]; i2 = e; }
      float tt = expf(v2 - v1);
      float w1 = 1.0f / (1.0f + tt);
      float w2 = tt / (1.0f + tt);
      top_idx[tok * 2] = i1; top_idx[tok * 2 + 1] = i2;
      top_w[tok * 2] = w1;  top_w[tok * 2 + 1] = w2;
      atomicAdd(&hist[i1], 1); atomicAdd(&hist[i2], 1);
    }
  }
  __syncthreads();
  if (tid < 16) atomicAdd(&counts[tid], hist[tid]);
}

// ---------------- scatter: local scan of counts, block-aggregated reservation.
// pair_tok packs token | (k<<16).
__global__ __launch_bounds__(256) void scatter_kernel(const int* __restrict__ top_idx,
                                                      const float* __restrict__ top_w,
                                                      const int* __restrict__ counts,
                                                      int* __restrict__ cursor,
                                                      int* __restrict__ pair_tok,
                                                      float* __restrict__ pair_w){
  __shared__ int hist[16], base[16], rank[16], offs[16];
  int tid = threadIdx.x;
  if (tid < 16){ hist[tid] = 0; rank[tid] = 0; }
  __syncthreads();
  int t = blockIdx.x * 256 + tid;
  int e0 = top_idx[t * 2], e1 = top_idx[t * 2 + 1];
  float w0 = top_w[t * 2], w1 = top_w[t * 2 + 1];
  atomicAdd(&hist[e0], 1); atomicAdd(&hist[e1], 1);
  if (tid < 64){                      // wave 0: exclusive scan of counts
    int lane = tid;
    int c = (lane < 16) ? counts[lane] : 0;
    int s = c;
#pragma unroll
    for (int off = 1; off < 16; off <<= 1){ int o = __shfl_up(s, off, 64); if (lane >= off) s += o; }
    if (lane < 16) offs[lane] = s - c;
  }
  __syncthreads();
  if (tid < 16) base[tid] = offs[tid] + atomicAdd(&cursor[tid], hist[tid]);
  __syncthreads();
  int r0 = atomicAdd(&rank[e0], 1);
  int p0 = base[e0] + r0;
  pair_tok[p0] = t; pair_w[p0] = w0;
  int r1 = atomicAdd(&rank[e1], 1);
  int p1 = base[e1] + r1;
  pair_tok[p1] = t | (1 << 16); pair_w[p1] = w1;
}

// ---------------- fused 2-layer expert MLP (R19 internals + T5 setprio).
// 32x32 MFMA, 16-granule XOR swizzles, dbuf global_load_lds staging, raw
// barriers, persistent per-XCD stealing, in-kernel unit mapping from counts.
__global__ __launch_bounds__(512, 1) void moe_gemm_kernel(
    const unsigned short* __restrict__ x_bf,   // [B][256]
    const unsigned short* __restrict__ W1t,    // [E][512 h][256 i]
    const unsigned short* __restrict__ W2c,    // [E][8 c][256 o][64 h]
    const float* __restrict__ b1,              // [E][512]
    const float* __restrict__ b2,              // [E][256]
    const int* __restrict__ pair_tok, const float* __restrict__ pair_w,
    const int* __restrict__ counts,
    int* __restrict__ xcd_cur,
    unsigned short* __restrict__ ypair){       // [B*2][256] bf16, token-major
  int xcd = blockIdx.x & 7;

  __shared__ unsigned short w1s[2][CH * 256];   // 2x32KB [64 hid][256 k], 512B rows, ^(hid&15)<<4
  __shared__ unsigned short w2s[2][256 * CH];   // 2x32KB [256 o][64 k], 256B row-pairs, ^(pair&15)<<4
  __shared__ unsigned short hs[BM * CH];        // 16KB [128 tok][64 h], 256B row-pairs, ^(pair&15)<<4
  __shared__ int s_map[6];
  __shared__ int s_u;

  int tid = threadIdx.x, wid = tid >> 6, lane = tid & 63;
  int l31 = lane & 31, l5 = lane >> 5;
  int mg = wid >> 1, hg = wid & 1;
  char* hsb = (char*)hs;

  // ---- derive this XCD's (expert, start, count) mapping from counts
  if (tid < 64){
    int c = (lane < 16) ? counts[lane] : 0;
    int s = c;
#pragma unroll
    for (int off = 1; off < 16; off <<= 1){ int o = __shfl_up(s, off, 64); if (lane >= off) s += o; }
    int start = s - c;
    int c0 = __shfl(c, xcd, 64),     st0 = __shfl(start, xcd, 64);
    int c1 = __shfl(c, xcd + 8, 64), st1 = __shfl(start, xcd + 8, 64);
    if (lane == 0){
      int nb0 = (c0 + BM - 1) >> 7, nb1 = (c1 + BM - 1) >> 7;
      s_map[0] = c0; s_map[1] = st0; s_map[2] = c1; s_map[3] = st1;
      s_map[4] = nb0; s_map[5] = nb0 + nb1;
    }
  }
  __syncthreads();
  int mc0 = s_map[0], mst0 = s_map[1], mc1 = s_map[2], mst1 = s_map[3];
  int nb0 = s_map[4], cnt = s_map[5];

  // pre-swizzled staging source offsets (linear LDS dest; +k*8192 preserves XOR bits)
  int o1, o2;
  { int r = tid >> 5; o1 = r * 512 + (((tid & 31) ^ (r & 15)) * 16); }
  { int p = tid >> 4; int q = (tid & 15) ^ (p & 15);
    o2 = (p * 2 + (q >> 3)) * 128 + (q & 7) * 16; }

  int hid = hg * 32 + l31;                 // chunk-local hid row this wave reads/writes
  int swzA = (hid & 15) << 4;
  const f32x16 fzero = {0.f,0.f,0.f,0.f,0.f,0.f,0.f,0.f,0.f,0.f,0.f,0.f,0.f,0.f,0.f,0.f};

  for (;;){
    if (tid == 0) s_u = atomicAdd(&xcd_cur[xcd], 1);
    __syncthreads();
    int u = s_u;
    if (u >= cnt) break;                   // uniform exit
    int e, rs, re;
    if (u < nb0){ e = xcd;     rs = mst0 + u * BM;         re = mst0 + mc0; }
    else        { e = xcd + 8; rs = mst1 + (u - nb0) * BM; re = mst1 + mc1; }
    const char* gW1 = (const char*)(W1t + (size_t)e * DHID * DIN);
    const char* gW2 = (const char*)(W2c + (size_t)e * DOUT * DHID);

#define STAGE(c, sl) {                                                    \
    const char* s1 = gW1 + (size_t)(c) * 32768;                           \
    const char* s2 = gW2 + (size_t)(c) * 32768;                           \
    char* d1 = (char*)w1s[sl]; char* d2 = (char*)w2s[sl];                 \
    _Pragma("unroll")                                                     \
    for (int k = 0; k < 4; k++){                                          \
      gload16(s1 + o1 + k * 8192, d1 + tid * 16 + k * 8192);              \
      gload16(s2 + o2 + k * 8192, d2 + tid * 16 + k * 8192);              \
    } }

    // ---- x rows (wave's 32 tokens) -> registers: 16 k-frags (64 VGPR)
    bf16x8 xr[16];
    {
      int g0 = rs + mg * 32 + l31;
      int gc = g0 < re ? g0 : (re - 1);
      int tok = pair_tok[gc] & 0xFFFF;
      const unsigned short* xrow = x_bf + (size_t)tok * DIN + l5 * 8;
#pragma unroll
      for (int ks = 0; ks < 16; ks++) xr[ks] = *(const bf16x8*)(xrow + ks * 16);
    }

    f32x16 acc[4];
    acc[0] = fzero; acc[1] = fzero; acc[2] = fzero; acc[3] = fzero;

    STAGE(0, 0);
    asm volatile("s_waitcnt vmcnt(0)" ::: "memory");
    __builtin_amdgcn_sched_barrier(0);
    __builtin_amdgcn_s_barrier();
    __builtin_amdgcn_sched_barrier(0);

    for (int c = 0; c < NCH; c++){
      int sl = c & 1;
      if (c + 1 < NCH) STAGE(c + 1, sl ^ 1);     // lands during this chunk

      float b1v = b1[e * DHID + c * CH + hid];

      // ---- phase A: h-tile[32 tok of mg][32 hid of hg], K=256, 2 dep-chains
      {
        const char* w1b = (const char*)w1s[sl];
        f32x16 h0 = fzero, h1 = fzero;
        __builtin_amdgcn_s_setprio(1);
#pragma unroll
        for (int ks = 0; ks < 16; ks += 2){
          bf16x8 bA = *(const bf16x8*)(w1b + hid * 512 + ((ks * 32 + l5 * 16) ^ swzA));
          bf16x8 bB = *(const bf16x8*)(w1b + hid * 512 + (((ks + 1) * 32 + l5 * 16) ^ swzA));
          h0 = __builtin_amdgcn_mfma_f32_32x32x16_bf16(xr[ks], bA, h0, 0, 0, 0);
          h1 = __builtin_amdgcn_mfma_f32_32x32x16_bf16(xr[ks + 1], bB, h1, 0, 0, 0);
        }
        __builtin_amdgcn_s_setprio(0);
        f32x16 hsum = h0 + h1;
        // relu(h+b1) -> hs; C/D: col=lane&31, row=(reg&3)+8*(reg>>2)+4*(lane>>5)
        int h2 = hg * 64 + l31 * 2;
#pragma unroll
        for (int r = 0; r < 16; r++){
          int tk = mg * 32 + (r & 3) + ((r >> 2) << 3) + (l5 << 2);
          float v = fmaxf(hsum[r] + b1v, 0.f);
          int adr = (tk >> 1) * 256 + ((((tk & 1) << 7) + h2) ^ (((tk >> 1) & 15) << 4));
          *(unsigned short*)(hsb + adr) = f2bf(v);
        }
      }
      asm volatile("s_waitcnt lgkmcnt(0)" ::: "memory");
      __builtin_amdgcn_sched_barrier(0);
      __builtin_amdgcn_s_barrier();
      __builtin_amdgcn_sched_barrier(0);

      // ---- phase B: y[32 tok of mg][128 out of hg] += h @ W2c (K=64)
      {
        const char* w2b = (const char*)w2s[sl];
        int tk = mg * 32 + l31;
        int hswz = ((tk >> 1) & 15) << 4;
        int hbase = (tk >> 1) * 256;
        int hhi = (tk & 1) << 7;
        __builtin_amdgcn_s_setprio(1);
#pragma unroll
        for (int ks = 0; ks < 4; ks++){
          bf16x8 ha = *(const bf16x8*)(hsb + hbase + ((hhi + ks * 32 + l5 * 16) ^ hswz));
#pragma unroll
          for (int ot = 0; ot < 4; ot++){
            int n = hg * 128 + ot * 32 + l31;
            int adr = (n >> 1) * 256 + ((((n & 1) << 7) + ks * 32 + l5 * 16) ^ (((n >> 1) & 15) << 4));
            bf16x8 bb = *(const bf16x8*)(w2b + adr);
            acc[ot] = __builtin_amdgcn_mfma_f32_32x32x16_bf16(ha, bb, acc[ot], 0, 0, 0);
          }
        }
        __builtin_amdgcn_s_setprio(0);
      }
      if (c + 1 < NCH){
        asm volatile("s_waitcnt vmcnt(0) lgkmcnt(0)" ::: "memory");
        __builtin_amdgcn_sched_barrier(0);
        __builtin_amdgcn_s_barrier();
        __builtin_amdgcn_sched_barrier(0);
      }
    }

    // ---- epilogue: fold gate weight + b2, store token-major bf16 rows
    {
      float b2v[4];
#pragma unroll
      for (int ot = 0; ot < 4; ot++) b2v[ot] = b2[e * DOUT + hg * 128 + ot * 32 + l31];
#pragma unroll
      for (int r = 0; r < 16; r++){
        int tl = mg * 32 + (r & 3) + ((r >> 2) << 3) + (l5 << 2);
        int gg = rs + tl;
        if (gg < re){
          int pt = pair_tok[gg];
          int yrow = (pt & 0xFFFF) * 2 + (pt >> 16);
          float w = pair_w[gg];
          unsigned short* yp = ypair + (size_t)yrow * DOUT + hg * 128 + l31;
#pragma unroll
          for (int ot = 0; ot < 4; ot++)
            yp[ot * 32] = f2bf(w * (acc[ot][r] + b2v[ot]));
        }
      }
    }
#undef STAGE
  }
}

// ---------------- combine: out[t] = yp[2t] + yp[2t+1], fully coalesced
__global__ __launch_bounds__(256) void combine_kernel(const unsigned short* __restrict__ yp,
                                                      float* __restrict__ out){
  int idx = blockIdx.x * 256 + threadIdx.x;
  int t = idx >> 6;
  int c4 = (idx & 63) << 2;
  ushort4 a = *(const ushort4*)(yp + (size_t)(t * 2) * DOUT + c4);
  ushort4 b = *(const ushort4*)(yp + (size_t)(t * 2 + 1) * DOUT + c4);
  float4 o;
  o.x = bf2f(a.x) + bf2f(b.x);
  o.y = bf2f(a.y) + bf2f(b.y);
  o.z = bf2f(a.z) + bf2f(b.z);
  o.w = bf2f(a.w) + bf2f(b.w);
  *(float4*)(out + (size_t)t * DOUT + c4) = o;
}

extern "C" void kernel_launch(void* const* d_in, const int* in_sizes, int n_in,
                              void* d_out, int out_size, void* d_ws, size_t ws_size,
                              hipStream_t stream){
  (void)in_sizes; (void)n_in; (void)out_size; (void)ws_size;
  const float* x  = (const float*)d_in[0];
  const float* Wg = (const float*)d_in[1];
  const float* bg = (const float*)d_in[2];
  const float* W1 = (const float*)d_in[3];
  const float* b1 = (const float*)d_in[4];
  const float* W2 = (const float*)d_in[5];
  const float* b2 = (const float*)d_in[6];
  float* out = (float*)d_out;
  char* ws = (char*)d_ws;

  unsigned short* x_bf  = (unsigned short*)(ws);                 // 16,777,216
  unsigned short* W1t   = (unsigned short*)(ws + 16777216);      //  4,194,304
  unsigned short* W2ck  = (unsigned short*)(ws + 20971520);      //  4,194,304
  unsigned short* ypair = (unsigned short*)(ws + 25165824);      // 33,554,432
  int*   top_idx  = (int*)  (ws + 58720256);
  float* top_w    = (float*)(ws + 58982400);
  int*   pair_tok = (int*)  (ws + 59244544);
  float* pair_w   = (float*)(ws + 59506688);
  int*   counts   = (int*)  (ws + 60030976);   // 16 ints
  int*   cursor   = (int*)  (ws + 60031040);   // 16 ints
  int*   xcd_cur  = (int*)  (ws + 60031104);   // 8 ints

  hipMemsetAsync(counts, 0, 192, stream);      // counts + cursor + xcd_cur
  transpose_fused<<<4096, 256, 0, stream>>>(W1, W2, W1t, W2ck);
  gating_kernel<<<512, 256, 0, stream>>>(x, Wg, bg, x_bf, top_idx, top_w, counts);
  scatter_kernel<<<128, 256, 0, stream>>>(top_idx, top_w, counts, cursor, pair_tok, pair_w);
  moe_gemm_kernel<<<256, 512, 0, stream>>>(x_bf, W1t, W2ck, b1, b2, pair_tok, pair_w,
                                           counts, xcd_cur, ypair);
  combine_kernel<<<8192, 256, 0, stream>>>(ypair, out);
}

// Round 22
// 148.654 us; speedup vs baseline: 1.1874x; 1.0021x over previous
//
#include <hip/hip_runtime.h>
#include <stdint.h>

#define BTOK 32768
#define DIN 256
#define DHID 512
#define DOUT 256
#define NEXP 16
#define BM 128
#define CH 64
#define NCH 8

typedef __attribute__((ext_vector_type(8))) short bf16x8;
typedef __attribute__((ext_vector_type(16))) float f32x16;

__device__ __forceinline__ unsigned short f2bf(float f){
  unsigned u = __builtin_bit_cast(unsigned, f);
  u = u + 0x7FFFu + ((u >> 16) & 1u);      // RNE, finite inputs only
  return (unsigned short)(u >> 16);
}
__device__ __forceinline__ float bf2f(unsigned short h){
  return __builtin_bit_cast(float, (unsigned)h << 16);
}
__device__ __forceinline__ void gload16(const void* g, void* l){
  __builtin_amdgcn_global_load_lds((const __attribute__((address_space(1))) unsigned int*)g,
                                   (__attribute__((address_space(3))) unsigned int*)l, 16, 0, 0);
}

// ---------------- fused weight transposes (one launch, 4096 blocks, 4.2KB LDS)
__global__ __launch_bounds__(256) void transpose_fused(const float* __restrict__ W1,
                                                       const float* __restrict__ W2,
                                                       unsigned short* __restrict__ W1t,
                                                       unsigned short* __restrict__ W2c){
  __shared__ float t[32][33];
  int bid = blockIdx.x, tid = threadIdx.x;
  int lx = tid & 31, ly = tid >> 5;
  if (bid < 2048){
    int bx = bid & 15, by = (bid >> 4) & 7, bz = bid >> 7;
    int r0 = by * 32, c0 = bx * 32;            // r0 over i (256), c0 over h (512)
    const float* s = W1 + (size_t)bz * 256 * 512;
    unsigned short* d = W1t + (size_t)bz * 256 * 512;
#pragma unroll
    for (int i = 0; i < 4; i++){ int r = ly + i * 8; t[r][lx] = s[(size_t)(r0 + r) * 512 + c0 + lx]; }
    __syncthreads();
#pragma unroll
    for (int i = 0; i < 4; i++){ int r = ly + i * 8; d[(size_t)(c0 + r) * 256 + r0 + lx] = f2bf(t[lx][r]); }
  } else {
    int b2 = bid - 2048;
    int bx = b2 & 7, by = (b2 >> 3) & 15, bz = b2 >> 7;
    int r0 = by * 32, c0 = bx * 32;            // r0 over h (512), c0 over o (256)
    const float* s = W2 + (size_t)bz * DHID * DOUT;
    unsigned short* d = W2c + (size_t)bz * DHID * DOUT + (r0 >> 6) * (DOUT * CH) + (r0 & 32);
#pragma unroll
    for (int i = 0; i < 4; i++){ int r = ly + i * 8; t[r][lx] = s[(size_t)(r0 + r) * DOUT + c0 + lx]; }
    __syncthreads();
#pragma unroll
    for (int i = 0; i < 4; i++){ int rr = ly + i * 8; d[(size_t)(c0 + rr) * CH + lx] = f2bf(t[lx][rr]); }
  }
}

// ---------------- gating: 512 blocks x 64 tokens; LDS-aggregated histogram
__global__ __launch_bounds__(256) void gating_kernel(const float* __restrict__ x,
                                                     const float* __restrict__ Wg,
                                                     const float* __restrict__ bg,
                                                     unsigned short* __restrict__ x_bf,
                                                     int* __restrict__ top_idx,
                                                     float* __restrict__ top_w,
                                                     int* __restrict__ counts){
  __shared__ float WgT[16][256];
  __shared__ int hist[16];
  int tid = threadIdx.x;
#pragma unroll
  for (int j = 0; j < 4; j++){
    float4 wv = *(const float4*)(Wg + tid * 16 + j * 4);
    WgT[j * 4 + 0][tid] = wv.x; WgT[j * 4 + 1][tid] = wv.y;
    WgT[j * 4 + 2][tid] = wv.z; WgT[j * 4 + 3][tid] = wv.w;
  }
  if (tid < 16) hist[tid] = 0;
  __syncthreads();
  int wid = tid >> 6, lane = tid & 63;

  for (int t = 0; t < 16; t++){
    int tok = blockIdx.x * 64 + wid * 16 + t;
    const float4 xv = *(const float4*)(x + (size_t)tok * DIN + lane * 4);
    ushort4 xb; xb.x = f2bf(xv.x); xb.y = f2bf(xv.y); xb.z = f2bf(xv.z); xb.w = f2bf(xv.w);
    *(ushort4*)(x_bf + (size_t)tok * DIN + lane * 4) = xb;
    float logit[16];
#pragma unroll
    for (int e = 0; e < 16; e++){
      const float4 wv = *(const float4*)(&WgT[e][lane * 4]);
      float v = xv.x * wv.x + xv.y * wv.y + xv.z * wv.z + xv.w * wv.w;
#pragma unroll
      for (int off = 32; off; off >>= 1) v += __shfl_xor(v, off, 64);
      logit[e] = v + bg[e];
    }
    if (lane == 0){
      int i1 = 0; float v1 = logit[0];
#pragma unroll
      for (int e = 1; e < 16; e++) if (logit[e] > v1){ v1 = logit[e]; i1 = e; }
      int i2 = -1; float v2 = -3.4e38f;
#pragma unroll
      for (int e = 0; e < 16; e++) if (e != i1 && logit[e] > v2){ v2 = logit[e]; i2 = e; }
      float tt = expf(v2 - v1);
      float w1 = 1.0f / (1.0f + tt);
      float w2 = tt / (1.0f + tt);
      top_idx[tok * 2] = i1; top_idx[tok * 2 + 1] = i2;
      top_w[tok * 2] = w1;  top_w[tok * 2 + 1] = w2;
      atomicAdd(&hist[i1], 1); atomicAdd(&hist[i2], 1);
    }
  }
  __syncthreads();
  if (tid < 16) atomicAdd(&counts[tid], hist[tid]);
}

// ---------------- scatter: local scan of counts, block-aggregated reservation.
__global__ __launch_bounds__(256) void scatter_kernel(const int* __restrict__ top_idx,
                                                      const float* __restrict__ top_w,
                                                      const int* __restrict__ counts,
                                                      int* __restrict__ cursor,
                                                      int* __restrict__ pair_tok,
                                                      float* __restrict__ pair_w){
  __shared__ int hist[16], base[16], rank[16], offs[16];
  int tid = threadIdx.x;
  if (tid < 16){ hist[tid] = 0; rank[tid] = 0; }
  __syncthreads();
  int t = blockIdx.x * 256 + tid;
  int e0 = top_idx[t * 2], e1 = top_idx[t * 2 + 1];
  float w0 = top_w[t * 2], w1 = top_w[t * 2 + 1];
  atomicAdd(&hist[e0], 1); atomicAdd(&hist[e1], 1);
  if (tid < 64){                      // wave 0: exclusive scan of counts
    int lane = tid;
    int c = (lane < 16) ? counts[lane] : 0;
    int s = c;
#pragma unroll
    for (int off = 1; off < 16; off <<= 1){ int o = __shfl_up(s, off, 64); if (lane >= off) s += o; }
    if (lane < 16) offs[lane] = s - c;
  }
  __syncthreads();
  if (tid < 16) base[tid] = offs[tid] + atomicAdd(&cursor[tid], hist[tid]);
  __syncthreads();
  int r0 = atomicAdd(&rank[e0], 1);
  int p0 = base[e0] + r0;
  pair_tok[p0] = t; pair_w[p0] = w0;
  int r1 = atomicAdd(&rank[e1], 1);
  int p1 = base[e1] + r1;
  pair_tok[p1] = t | (1 << 16); pair_w[p1] = w1;
}

// ---------------- fused 2-layer expert MLP (R21 + b1->LDS: removes the hidden
// mid-chunk vmcnt(0) drain caused by the per-chunk global b1 load sitting
// BEHIND the STAGE(c+1) loads in the vmem FIFO). 32x32 MFMA, 16-granule XOR
// swizzles, dbuf global_load_lds, raw barriers, setprio, persistent stealing.
__global__ __launch_bounds__(512, 1) void moe_gemm_kernel(
    const unsigned short* __restrict__ x_bf,   // [B][256]
    const unsigned short* __restrict__ W1t,    // [E][512 h][256 i]
    const unsigned short* __restrict__ W2c,    // [E][8 c][256 o][64 h]
    const float* __restrict__ b1,              // [E][512]
    const float* __restrict__ b2,              // [E][256]
    const int* __restrict__ pair_tok, const float* __restrict__ pair_w,
    const int* __restrict__ counts,
    int* __restrict__ xcd_cur,
    unsigned short* __restrict__ ypair){       // [B*2][256] bf16, token-major
  int xcd = blockIdx.x & 7;

  __shared__ unsigned short w1s[2][CH * 256];   // 2x32KB [64 hid][256 k], 512B rows, ^(hid&15)<<4
  __shared__ unsigned short w2s[2][256 * CH];   // 2x32KB [256 o][64 k], 256B row-pairs, ^(pair&15)<<4
  __shared__ unsigned short hs[BM * CH];        // 16KB [128 tok][64 h], 256B row-pairs, ^(pair&15)<<4
  __shared__ float b1s[DHID];                   // 2KB, per-unit bias (lgkm-side)
  __shared__ int s_map[6];
  __shared__ int s_u;

  int tid = threadIdx.x, wid = tid >> 6, lane = tid & 63;
  int l31 = lane & 31, l5 = lane >> 5;
  int mg = wid >> 1, hg = wid & 1;
  char* hsb = (char*)hs;

  // ---- derive this XCD's (expert, start, count) mapping from counts
  if (tid < 64){
    int c = (lane < 16) ? counts[lane] : 0;
    int s = c;
#pragma unroll
    for (int off = 1; off < 16; off <<= 1){ int o = __shfl_up(s, off, 64); if (lane >= off) s += o; }
    int start = s - c;
    int c0 = __shfl(c, xcd, 64),     st0 = __shfl(start, xcd, 64);
    int c1 = __shfl(c, xcd + 8, 64), st1 = __shfl(start, xcd + 8, 64);
    if (lane == 0){
      int nb0 = (c0 + BM - 1) >> 7, nb1 = (c1 + BM - 1) >> 7;
      s_map[0] = c0; s_map[1] = st0; s_map[2] = c1; s_map[3] = st1;
      s_map[4] = nb0; s_map[5] = nb0 + nb1;
    }
  }
  __syncthreads();
  int mc0 = s_map[0], mst0 = s_map[1], mc1 = s_map[2], mst1 = s_map[3];
  int nb0 = s_map[4], cnt = s_map[5];

  // pre-swizzled staging source offsets (linear LDS dest; +k*8192 preserves XOR bits)
  int o1, o2;
  { int r = tid >> 5; o1 = r * 512 + (((tid & 31) ^ (r & 15)) * 16); }
  { int p = tid >> 4; int q = (tid & 15) ^ (p & 15);
    o2 = (p * 2 + (q >> 3)) * 128 + (q & 7) * 16; }

  int hid = hg * 32 + l31;                 // chunk-local hid row this wave reads/writes
  int swzA = (hid & 15) << 4;
  const f32x16 fzero = {0.f,0.f,0.f,0.f,0.f,0.f,0.f,0.f,0.f,0.f,0.f,0.f,0.f,0.f,0.f,0.f};

  for (;;){
    if (tid == 0) s_u = atomicAdd(&xcd_cur[xcd], 1);
    __syncthreads();
    int u = s_u;
    if (u >= cnt) break;                   // uniform exit
    int e, rs, re;
    if (u < nb0){ e = xcd;     rs = mst0 + u * BM;         re = mst0 + mc0; }
    else        { e = xcd + 8; rs = mst1 + (u - nb0) * BM; re = mst1 + mc1; }
    const char* gW1 = (const char*)(W1t + (size_t)e * DHID * DIN);
    const char* gW2 = (const char*)(W2c + (size_t)e * DOUT * DHID);

#define STAGE(c, sl) {                                                    \
    const char* s1 = gW1 + (size_t)(c) * 32768;                           \
    const char* s2 = gW2 + (size_t)(c) * 32768;                           \
    char* d1 = (char*)w1s[sl]; char* d2 = (char*)w2s[sl];                 \
    _Pragma("unroll")                                                     \
    for (int k = 0; k < 4; k++){                                          \
      gload16(s1 + o1 + k * 8192, d1 + tid * 16 + k * 8192);              \
      gload16(s2 + o2 + k * 8192, d2 + tid * 16 + k * 8192);              \
    } }

    // ---- b1 -> LDS once per unit (keeps per-chunk bias off the vmem FIFO)
    b1s[tid] = b1[e * DHID + tid];

    // ---- x rows (wave's 32 tokens) -> registers: 16 k-frags (64 VGPR)
    bf16x8 xr[16];
    {
      int g0 = rs + mg * 32 + l31;
      int gc = g0 < re ? g0 : (re - 1);
      int tok = pair_tok[gc] & 0xFFFF;
      const unsigned short* xrow = x_bf + (size_t)tok * DIN + l5 * 8;
#pragma unroll
      for (int ks = 0; ks < 16; ks++) xr[ks] = *(const bf16x8*)(xrow + ks * 16);
    }

    f32x16 acc[4];
    acc[0] = fzero; acc[1] = fzero; acc[2] = fzero; acc[3] = fzero;

    STAGE(0, 0);
    asm volatile("s_waitcnt vmcnt(0) lgkmcnt(0)" ::: "memory");   // b1s ds_writes drained too
    __builtin_amdgcn_sched_barrier(0);
    __builtin_amdgcn_s_barrier();
    __builtin_amdgcn_sched_barrier(0);

    for (int c = 0; c < NCH; c++){
      int sl = c & 1;
      if (c + 1 < NCH) STAGE(c + 1, sl ^ 1);     // lands during this chunk

      // ---- phase A: h-tile[32 tok of mg][32 hid of hg], K=256, 2 dep-chains
      {
        const char* w1b = (const char*)w1s[sl];
        f32x16 h0 = fzero, h1 = fzero;
        __builtin_amdgcn_s_setprio(1);
#pragma unroll
        for (int ks = 0; ks < 16; ks += 2){
          bf16x8 bA = *(const bf16x8*)(w1b + hid * 512 + ((ks * 32 + l5 * 16) ^ swzA));
          bf16x8 bB = *(const bf16x8*)(w1b + hid * 512 + (((ks + 1) * 32 + l5 * 16) ^ swzA));
          h0 = __builtin_amdgcn_mfma_f32_32x32x16_bf16(xr[ks], bA, h0, 0, 0, 0);
          h1 = __builtin_amdgcn_mfma_f32_32x32x16_bf16(xr[ks + 1], bB, h1, 0, 0, 0);
        }
        __builtin_amdgcn_s_setprio(0);
        f32x16 hsum = h0 + h1;
        float b1v = b1s[c * CH + hid];             // LDS read, lgkm-side
        // relu(h+b1) -> hs; C/D: col=lane&31, row=(reg&3)+8*(reg>>2)+4*(lane>>5)
        int h2 = hg * 64 + l31 * 2;
#pragma unroll
        for (int r = 0; r < 16; r++){
          int tk = mg * 32 + (r & 3) + ((r >> 2) << 3) + (l5 << 2);
          float v = fmaxf(hsum[r] + b1v, 0.f);
          int adr = (tk >> 1) * 256 + ((((tk & 1) << 7) + h2) ^ (((tk >> 1) & 15) << 4));
          *(unsigned short*)(hsb + adr) = f2bf(v);
        }
      }
      asm volatile("s_waitcnt lgkmcnt(0)" ::: "memory");
      __builtin_amdgcn_sched_barrier(0);
      __builtin_amdgcn_s_barrier();
      __builtin_amdgcn_sched_barrier(0);

      // ---- phase B: y[32 tok of mg][128 out of hg] += h @ W2c (K=64)
      {
        const char* w2b = (const char*)w2s[sl];
        int tk = mg * 32 + l31;
        int hswz = ((tk >> 1) & 15) << 4;
        int hbase = (tk >> 1) * 256;
        int hhi = (tk & 1) << 7;
        __builtin_amdgcn_s_setprio(1);
#pragma unroll
        for (int ks = 0; ks < 4; ks++){
          bf16x8 ha = *(const bf16x8*)(hsb + hbase + ((hhi + ks * 32 + l5 * 16) ^ hswz));
#pragma unroll
          for (int ot = 0; ot < 4; ot++){
            int n = hg * 128 + ot * 32 + l31;
            int adr = (n >> 1) * 256 + ((((n & 1) << 7) + ks * 32 + l5 * 16) ^ (((n >> 1) & 15) << 4));
            bf16x8 bb = *(const bf16x8*)(w2b + adr);
            acc[ot] = __builtin_amdgcn_mfma_f32_32x32x16_bf16(ha, bb, acc[ot], 0, 0, 0);
          }
        }
        __builtin_amdgcn_s_setprio(0);
      }
      if (c + 1 < NCH){
        asm volatile("s_waitcnt vmcnt(0) lgkmcnt(0)" ::: "memory");
        __builtin_amdgcn_sched_barrier(0);
        __builtin_amdgcn_s_barrier();
        __builtin_amdgcn_sched_barrier(0);
      }
    }

    // ---- epilogue: fold gate weight + b2, store token-major bf16 rows
    {
      float b2v[4];
#pragma unroll
      for (int ot = 0; ot < 4; ot++) b2v[ot] = b2[e * DOUT + hg * 128 + ot * 32 + l31];
#pragma unroll
      for (int r = 0; r < 16; r++){
        int tl = mg * 32 + (r & 3) + ((r >> 2) << 3) + (l5 << 2);
        int gg = rs + tl;
        if (gg < re){
          int pt = pair_tok[gg];
          int yrow = (pt & 0xFFFF) * 2 + (pt >> 16);
          float w = pair_w[gg];
          unsigned short* yp = ypair + (size_t)yrow * DOUT + hg * 128 + l31;
#pragma unroll
          for (int ot = 0; ot < 4; ot++)
            yp[ot * 32] = f2bf(w * (acc[ot][r] + b2v[ot]));
        }
      }
    }
#undef STAGE
  }
}

// ---------------- combine: out[t] = yp[2t] + yp[2t+1], 8 floats/thread
__global__ __launch_bounds__(256) void combine_kernel(const unsigned short* __restrict__ yp,
                                                      float* __restrict__ out){
  int idx = blockIdx.x * 256 + threadIdx.x;   // 4096 blocks
  int t = idx >> 5;
  int c8 = (idx & 31) << 3;
  uint4 a = *(const uint4*)(yp + (size_t)(t * 2) * DOUT + c8);
  uint4 b = *(const uint4*)(yp + (size_t)(t * 2 + 1) * DOUT + c8);
  float4 o0, o1;
  o0.x = bf2f((unsigned short)a.x) + bf2f((unsigned short)b.x);
  o0.y = bf2f((unsigned short)(a.x >> 16)) + bf2f((unsigned short)(b.x >> 16));
  o0.z = bf2f((unsigned short)a.y) + bf2f((unsigned short)b.y);
  o0.w = bf2f((unsigned short)(a.y >> 16)) + bf2f((unsigned short)(b.y >> 16));
  o1.x = bf2f((unsigned short)a.z) + bf2f((unsigned short)b.z);
  o1.y = bf2f((unsigned short)(a.z >> 16)) + bf2f((unsigned short)(b.z >> 16));
  o1.z = bf2f((unsigned short)a.w) + bf2f((unsigned short)b.w);
  o1.w = bf2f((unsigned short)(a.w >> 16)) + bf2f((unsigned short)(b.w >> 16));
  *(float4*)(out + (size_t)t * DOUT + c8) = o0;
  *(float4*)(out + (size_t)t * DOUT + c8 + 4) = o1;
}

extern "C" void kernel_launch(void* const* d_in, const int* in_sizes, int n_in,
                              void* d_out, int out_size, void* d_ws, size_t ws_size,
                              hipStream_t stream){
  (void)in_sizes; (void)n_in; (void)out_size; (void)ws_size;
  const float* x  = (const float*)d_in[0];
  const float* Wg = (const float*)d_in[1];
  const float* bg = (const float*)d_in[2];
  const float* W1 = (const float*)d_in[3];
  const float* b1 = (const float*)d_in[4];
  const float* W2 = (const float*)d_in[5];
  const float* b2 = (const float*)d_in[6];
  float* out = (float*)d_out;
  char* ws = (char*)d_ws;

  unsigned short* x_bf  = (unsigned short*)(ws);                 // 16,777,216
  unsigned short* W1t   = (unsigned short*)(ws + 16777216);      //  4,194,304
  unsigned short* W2ck  = (unsigned short*)(ws + 20971520);      //  4,194,304
  unsigned short* ypair = (unsigned short*)(ws + 25165824);      // 33,554,432
  int*   top_idx  = (int*)  (ws + 58720256);
  float* top_w    = (float*)(ws + 58982400);
  int*   pair_tok = (int*)  (ws + 59244544);
  float* pair_w   = (float*)(ws + 59506688);
  int*   counts   = (int*)  (ws + 60030976);   // 16 ints
  int*   cursor   = (int*)  (ws + 60031040);   // 16 ints
  int*   xcd_cur  = (int*)  (ws + 60031104);   // 8 ints

  hipMemsetAsync(counts, 0, 192, stream);      // counts + cursor + xcd_cur
  transpose_fused<<<4096, 256, 0, stream>>>(W1, W2, W1t, W2ck);
  gating_kernel<<<512, 256, 0, stream>>>(x, Wg, bg, x_bf, top_idx, top_w, counts);
  scatter_kernel<<<128, 256, 0, stream>>>(top_idx, top_w, counts, cursor, pair_tok, pair_w);
  moe_gemm_kernel<<<256, 512, 0, stream>>>(x_bf, W1t, W2ck, b1, b2, pair_tok, pair_w,
                                           counts, xcd_cur, ypair);
  combine_kernel<<<4096, 256, 0, stream>>>(ypair, out);
}